// Round 6
// baseline (126.718 us; speedup 1.0000x reference)
//
#include <hip/hip_runtime.h>

#define NG 3200
#define NF 17
#define RH 48
#define RW 88
#define NPIX (RH*RW)      // 4224
#define GTH 192
#define GTW 352
#define NCAM 2
#define CHUNK 40
#define NCHUNK 80         // CHUNK*NCHUNK == NG
#define CPW 10            // chunks per wave in k_loss (NCHUNK/8)
#define NLOSSBLK (NPIX/64*NCAM)   // 132
#define PREC 12           // dwords per pixel partial record (9 h2 + 3 pad)

typedef float v4f __attribute__((ext_vector_type(4)));
typedef _Float16 h2 __attribute__((ext_vector_type(2)));

// ws layout (dword offsets)
#define PS_OFF   0                                // sorted params [cam][r][8] (u,v,A2,B2,C2,op,0,0)
#define FS_OFF   (PS_OFF + NCAM*NG*8)             // sorted feats  [cam][r][20] (pad=0)
#define PT_OFF   (FS_OFF + NCAM*NG*20)            // partials [cam][chunk][NPIX][12]
#define ACC_OFF  (PT_OFF + NCAM*NCHUNK*NPIX*PREC) // num0,den0,num1,den1,ticket,...

__device__ __forceinline__ unsigned pack_h2(float a, float b){
  h2 r; r.x=(_Float16)a; r.y=(_Float16)b;
  unsigned u; __builtin_memcpy(&u,&r,4); return u;
}
__device__ __forceinline__ void unpack_h2(unsigned u, float& a, float& b){
  h2 r; __builtin_memcpy(&r,&u,4);
  a=(float)r.x; b=(float)r.y;
}

// ---------------- Kernel 1: fused projection/conic + stable z-rank + scatter ----------------
// One wave per gaussian (4/block). Block stages all z (computed on the fly) in LDS,
// wave counts stable rank, all lanes redundantly compute the conic, lanes scatter.
__global__ __launch_bounds__(256) void k_prep_sort(
    const float* __restrict__ vf, const float* __restrict__ opac,
    const float* __restrict__ xyz, const float* __restrict__ scales,
    const float* __restrict__ rots, const float* __restrict__ vm,
    const float* __restrict__ intr, float* __restrict__ ws)
{
  __shared__ float zsh[NG];
  int cam = blockIdx.y;
  const float* Vm = vm + cam*16;
  {
    float r20=Vm[8], r21=Vm[9], r22=Vm[10], t2c=Vm[11];
    for (int i=threadIdx.x; i<NG; i+=256)
      zsh[i] = fmaf(r20, xyz[i*3], fmaf(r21, xyz[i*3+1], fmaf(r22, xyz[i*3+2], t2c)));
  }
  if (blockIdx.x==0 && blockIdx.y==0 && threadIdx.x<8) ws[ACC_OFF+threadIdx.x]=0.f;
  __syncthreads();

  int wave = threadIdx.x >> 6, lane = threadIdx.x & 63;
  int g = blockIdx.x*4 + wave;          // grid.x = NG/4 = 800
  float zi = zsh[g];
  int rank = 0;
  #pragma unroll 5
  for (int k=0; k<NG/64; k++){
    int j = k*64 + lane;
    float zj = zsh[j];
    rank += ((zj < zi) || (zj == zi && j < g)) ? 1 : 0;
  }
  #pragma unroll
  for (int off=32; off>0; off>>=1) rank += __shfl_down(rank, off, 64);
  rank = __shfl(rank, 0, 64);

  // ---- conic (computed redundantly on all 64 lanes; loads are wave-uniform) ----
  float qw=rots[g*4+0], qx=rots[g*4+1], qy=rots[g*4+2], qz=rots[g*4+3];
  float qn = rsqrtf(qw*qw+qx*qx+qy*qy+qz*qz);
  qw*=qn; qx*=qn; qy*=qn; qz*=qn;
  float R[3][3];
  R[0][0]=1.f-2.f*(qy*qy+qz*qz); R[0][1]=2.f*(qx*qy-qw*qz); R[0][2]=2.f*(qx*qz+qw*qy);
  R[1][0]=2.f*(qx*qy+qw*qz); R[1][1]=1.f-2.f*(qx*qx+qz*qz); R[1][2]=2.f*(qy*qz-qw*qx);
  R[2][0]=2.f*(qx*qz-qw*qy); R[2][1]=2.f*(qy*qz+qw*qx); R[2][2]=1.f-2.f*(qx*qx+qy*qy);

  float s2[3];
  #pragma unroll
  for (int k=0;k<3;k++){ float s=expf(scales[g*3+k]); s2[k]=s*s; }

  float M[3][3];
  #pragma unroll
  for(int i=0;i<3;i++)
    #pragma unroll
    for(int j=0;j<3;j++)
      M[i][j] = R[i][0]*s2[0]*R[j][0] + R[i][1]*s2[1]*R[j][1] + R[i][2]*s2[2]*R[j][2];

  float Rw[3][3], t[3];
  #pragma unroll
  for(int i=0;i<3;i++){
    #pragma unroll
    for(int j=0;j<3;j++) Rw[i][j]=Vm[i*4+j];
    t[i]=Vm[i*4+3];
  }
  float T1[3][3];
  #pragma unroll
  for(int i=0;i<3;i++)
    #pragma unroll
    for(int j=0;j<3;j++)
      T1[i][j] = Rw[i][0]*M[0][j] + Rw[i][1]*M[1][j] + Rw[i][2]*M[2][j];
  float V[3][3];
  #pragma unroll
  for(int i=0;i<3;i++)
    #pragma unroll
    for(int j=0;j<3;j++)
      V[i][j] = T1[i][0]*Rw[j][0] + T1[i][1]*Rw[j][1] + T1[i][2]*Rw[j][2];

  float X=xyz[g*3+0], Y=xyz[g*3+1], Zp=xyz[g*3+2];
  float p0 = Rw[0][0]*X + Rw[0][1]*Y + Rw[0][2]*Zp + t[0];
  float p1 = Rw[1][0]*X + Rw[1][1]*Y + Rw[1][2]*Zp + t[1];

  float z  = zi;
  float zc = fmaxf(z, 0.2f);
  float fx=intr[cam*4+0], fy=intr[cam*4+1], cx=intr[cam*4+2], cy=intr[cam*4+3];
  float u = fx*p0/zc + cx;
  float v = fy*p1/zc + cy;

  float j00 = fx/zc, j02 = -fx*p0/(zc*zc);
  float j11 = fy/zc, j12 = -fy*p1/(zc*zc);
  float c00 = j00*j00*V[0][0] + 2.f*j00*j02*V[0][2] + j02*j02*V[2][2];
  float c01 = j00*(V[0][1]*j11 + V[0][2]*j12) + j02*(V[2][1]*j11 + V[2][2]*j12);
  float c11 = j11*j11*V[1][1] + 2.f*j11*j12*V[1][2] + j12*j12*V[2][2];

  float a = c00 + 0.3f, b = c01, c = c11 + 0.3f;
  float det = fmaxf(a*c - b*b, 1e-8f);
  // conic pre-scaled by -0.5*log2(e): power2 = A2 dx^2 + B2 dx dy + C2 dy^2,
  // alpha = opac * exp2(min(power2,0))
  const float L2E = 1.4426950408889634f;
  float A2 = -0.5f*L2E * (c/det);
  float B2 = -L2E * (-b/det);
  float C2 = -0.5f*L2E * (a/det);
  float opv = (z > 0.2f) ? opac[g] : 0.0f;

  float pv = (lane==0)?u:(lane==1)?v:(lane==2)?A2:(lane==3)?B2:(lane==4)?C2:(lane==5)?opv:0.f;
  if (lane < 8)  (ws + PS_OFF + (size_t)(cam*NG+rank)*8)[lane] = pv;
  if (lane < 20) (ws + FS_OFF + (size_t)(cam*NG+rank)*20)[lane] =
                    (lane < NF) ? vf[g*NF+lane] : 0.0f;
}

// ---------------- Kernel 2: chunked compositing, wave-skip + vector LDS ----------------
__global__ __launch_bounds__(192) void k_render(float* __restrict__ ws)
{
  __shared__ float4 sp4[CHUNK*2];   // u,v,A2,B2 | C2,op,_,_
  __shared__ float4 sf4[CHUNK*5];   // 20-float padded feats
  int cam = blockIdx.z, chunk = blockIdx.y;
  int g0 = chunk*CHUNK;
  const float4* psrc = (const float4*)(ws + PS_OFF) + (size_t)(cam*NG+g0)*2;
  for (int i=threadIdx.x; i<CHUNK*2; i+=192) sp4[i]=psrc[i];
  const float4* fsrc = (const float4*)(ws + FS_OFF) + (size_t)(cam*NG+g0)*5;
  for (int i=threadIdx.x; i<CHUNK*5; i+=192) sf4[i]=fsrc[i];
  __syncthreads();

  int pix = blockIdx.x*192 + threadIdx.x;       // 22*192 == NPIX, no guard
  float px = (float)(pix % RW), py = (float)(pix / RW);

  float T = 1.0f;
  v4f A[5];
  #pragma unroll
  for(int k=0;k<5;k++) A[k]=(v4f)(0.f);

  for (int g=0; g<CHUNK; g++){
    float4 q0 = sp4[g*2], q1 = sp4[g*2+1];
    float dx = px - q0.x, dy = py - q0.y;
    float power2 = fmaf(q1.x*dy, dy, dx*fmaf(q0.w, dy, q0.z*dx));
    // wave-uniform skip: alpha < op*2^-20 <= 1e-6 for ALL lanes -> negligible
    if (__any(power2 > -20.0f)) {
      float alpha = fminf(q1.y*exp2f(fminf(power2, 0.f)), 0.99f);
      float w = alpha*T;
      T = fmaf(-alpha, T, T);
      v4f wv; wv.x=w; wv.y=w; wv.z=w; wv.w=w;
      const v4f* f4 = (const v4f*)(sf4 + g*5);
      #pragma unroll
      for(int k=0;k<5;k++) A[k] += wv*f4[k];    // v_pk_fma_f32 x2 each
    }
  }

  union { v4f v[5]; float f[20]; } U;
  #pragma unroll
  for(int k=0;k<5;k++) U.v[k]=A[k];
  unsigned* rec = (unsigned*)(ws + PT_OFF)
                + ((size_t)(cam*NCHUNK+chunk)*NPIX + pix)*PREC;
  uint4 w0, w1;
  w0.x=pack_h2(U.f[0],U.f[1]);   w0.y=pack_h2(U.f[2],U.f[3]);
  w0.z=pack_h2(U.f[4],U.f[5]);   w0.w=pack_h2(U.f[6],U.f[7]);
  w1.x=pack_h2(U.f[8],U.f[9]);   w1.y=pack_h2(U.f[10],U.f[11]);
  w1.z=pack_h2(U.f[12],U.f[13]); w1.w=pack_h2(U.f[14],U.f[15]);
  *(uint4*)rec = w0;
  *((uint4*)rec + 1) = w1;
  rec[8] = pack_h2(U.f[16], T);
}

// ---------------- Kernel 3: fused combine + masked weighted CE + finalize ----------------
__global__ __launch_bounds__(512) void k_loss(
    const int* __restrict__ gt, const int* __restrict__ mask,
    const float* __restrict__ cw, float* __restrict__ ws, float* __restrict__ out)
{
  __shared__ float part[8*64*19];
  int cam = blockIdx.y;
  int wave = threadIdx.x >> 6, lane = threadIdx.x & 63;
  int pix = blockIdx.x*64 + lane;

  float F[NF];
  #pragma unroll
  for(int k=0;k<NF;k++) F[k]=0.f;
  float T = 1.f;
  #pragma unroll
  for (int i=0;i<CPW;i++){
    int c = wave*CPW + i;
    const unsigned* rec = (const unsigned*)(ws + PT_OFF)
                        + ((size_t)(cam*NCHUNK+c)*NPIX + pix)*PREC;
    uint4 a = *(const uint4*)rec;
    uint4 b = *((const uint4*)rec + 1);
    unsigned cc = rec[8];
    float v0,v1;
    unpack_h2(a.x,v0,v1); F[0]+=T*v0;  F[1]+=T*v1;
    unpack_h2(a.y,v0,v1); F[2]+=T*v0;  F[3]+=T*v1;
    unpack_h2(a.z,v0,v1); F[4]+=T*v0;  F[5]+=T*v1;
    unpack_h2(a.w,v0,v1); F[6]+=T*v0;  F[7]+=T*v1;
    unpack_h2(b.x,v0,v1); F[8]+=T*v0;  F[9]+=T*v1;
    unpack_h2(b.y,v0,v1); F[10]+=T*v0; F[11]+=T*v1;
    unpack_h2(b.z,v0,v1); F[12]+=T*v0; F[13]+=T*v1;
    unpack_h2(b.w,v0,v1); F[14]+=T*v0; F[15]+=T*v1;
    unpack_h2(cc, v0,v1); F[16]+=T*v0; T*=v1;
  }
  float* p = part + (wave*64 + lane)*19;
  #pragma unroll
  for(int k=0;k<NF;k++) p[k]=F[k];
  p[17]=T;
  __syncthreads();

  if (wave == 0){
    float img[NF];
    #pragma unroll
    for(int k=0;k<NF;k++) img[k]=0.f;
    float Trun = 1.f;
    for (int w=0; w<8; w++){
      const float* b = part + (w*64 + lane)*19;
      #pragma unroll
      for(int k=0;k<NF;k++) img[k] += Trun*b[k];
      Trun *= b[17];
    }
    int row = pix / RW, col = pix % RW;
    int gofs = cam*GTH*GTW + (row*4)*GTW + col*4;   // nearest resize: factor 4
    int gi = gt[gofs];
    float mi = (float)mask[gofs];
    float mx = img[0];
    #pragma unroll
    for(int k=1;k<NF;k++) mx = fmaxf(mx, img[k]);
    float s = 0.f;
    #pragma unroll
    for(int k=0;k<NF;k++) s += expf(img[k]-mx);
    float lse = mx + logf(s);
    float nll = lse - img[gi];
    float wi  = cw[gi]*mi;
    float num = wi*nll, den = wi;
    #pragma unroll
    for (int off=32; off>0; off>>=1){
      num += __shfl_down(num, off, 64);
      den += __shfl_down(den, off, 64);
    }
    if (lane == 0){
      atomicAdd(ws + ACC_OFF + cam*2 + 0, num);
      atomicAdd(ws + ACC_OFF + cam*2 + 1, den);
      __threadfence();
      int ticket = (int)atomicAdd(ws + ACC_OFF + 4, 1.0f);
      if (ticket == NLOSSBLK-1){
        float n0 = atomicAdd(ws + ACC_OFF + 0, 0.f);
        float d0 = atomicAdd(ws + ACC_OFF + 1, 0.f);
        float n1 = atomicAdd(ws + ACC_OFF + 2, 0.f);
        float d1 = atomicAdd(ws + ACC_OFF + 3, 0.f);
        float l0 = n0/fmaxf(d0, 1e-8f);
        float l1 = n1/fmaxf(d1, 1e-8f);
        out[0] = 0.5f*(l0 + l1);
      }
    }
  }
}

extern "C" void kernel_launch(void* const* d_in, const int* in_sizes, int n_in,
                              void* d_out, int out_size, void* d_ws, size_t ws_size,
                              hipStream_t stream) {
  const float* vf   = (const float*)d_in[0];
  const float* op   = (const float*)d_in[1];
  const float* xyz  = (const float*)d_in[2];
  const float* sc   = (const float*)d_in[3];
  const float* rt   = (const float*)d_in[4];
  const float* vm   = (const float*)d_in[5];
  const float* intr = (const float*)d_in[6];
  const float* cw   = (const float*)d_in[7];
  const int*   gt   = (const int*)d_in[8];
  const int*   mask = (const int*)d_in[9];
  float* ws  = (float*)d_ws;
  float* out = (float*)d_out;

  k_prep_sort<<<dim3(NG/4, NCAM), 256, 0, stream>>>(vf, op, xyz, sc, rt, vm, intr, ws);
  k_render   <<<dim3(NPIX/192, NCHUNK, NCAM), 192, 0, stream>>>(ws);
  k_loss     <<<dim3(NPIX/64, NCAM), 512, 0, stream>>>(gt, mask, cw, ws, out);
}